// Round 3
// baseline (741.031 us; speedup 1.0000x reference)
//
#include <hip/hip_runtime.h>
#include <stdint.h>

// Problem constants (match reference)
#define S_TOK 16384
#define MDIM  1024
#define NEXP  64
#define CAP   256   // ceil(S/E * 1.0), >= MIN_CAPACITY

static constexpr size_t SEC    = (size_t)S_TOK * NEXP * CAP;  // 268435456
static constexpr size_t CW_OFF = 1;                            // combine_weights
static constexpr size_t EC_OFF = 1 + 2 * SEC;                  // exp_counts (as float)
static constexpr size_t AL_OFF = EC_OFF + NEXP;                // alpha

typedef float floatx4 __attribute__((ext_vector_type(4)));     // clang vector (nontemporal-OK)

// ---------------- Threefry-2x32-20 == jax.random.uniform(key(42), (S,E)) ----------------
__device__ __forceinline__ uint32_t rotl32(uint32_t x, int n) {
  return (x << n) | (x >> (32 - n));
}

__device__ float jax_u01(uint32_t i) {
  const uint32_t half = (uint32_t)(S_TOK * NEXP / 2);  // 524288
  uint32_t x0, x1;
  const bool hi = (i >= half);
  if (hi) { x0 = i - half; x1 = i; } else { x0 = i; x1 = i + half; }
  const uint32_t ks0 = 0u;
  const uint32_t ks1 = 42u;
  const uint32_t ks2 = 0x1BD11BDAu ^ ks0 ^ ks1;
  x0 += ks0; x1 += ks1;
#define TF_R(r) { x0 += x1; x1 = rotl32(x1, (r)); x1 ^= x0; }
  TF_R(13) TF_R(15) TF_R(26) TF_R(6)
  x0 += ks1; x1 += ks2 + 1u;
  TF_R(17) TF_R(29) TF_R(16) TF_R(24)
  x0 += ks2; x1 += ks0 + 2u;
  TF_R(13) TF_R(15) TF_R(26) TF_R(6)
  x0 += ks0; x1 += ks1 + 3u;
  TF_R(17) TF_R(29) TF_R(16) TF_R(24)
  x0 += ks1; x1 += ks2 + 4u;
  TF_R(13) TF_R(15) TF_R(26) TF_R(6)
  x0 += ks2; x1 += ks0 + 5u;
#undef TF_R
  const uint32_t bits = hi ? x1 : x0;
  return __uint_as_float((bits >> 9) | 0x3F800000u) - 1.0f;  // [0,1)
}

// ---------------- K1: logits GEMM (fp32) + softmax + argmax/alpha/u/colsum ----------------
__global__ __launch_bounds__(256) void k_gate(
    const float* __restrict__ x, const float* __restrict__ wg,
    float* __restrict__ out,
    int* __restrict__ expert_ws, float* __restrict__ uval_ws,
    float* __restrict__ alpha_ws, float* __restrict__ colsum_ws)
{
  __shared__ float xs[64][68];   // 68-float rows keep float4 slots 16B-aligned
  __shared__ float wsh[64][68];

  const int tid  = threadIdx.x;
  const int tok0 = blockIdx.x * 64;
  const int tr   = tid >> 4;   // token group 0..15 (4 tokens each)
  const int tc   = tid & 15;   // expert group 0..15 (4 experts each)

  float acc[4][4] = {};

  for (int kc = 0; kc < MDIM; kc += 64) {
    __syncthreads();
#pragma unroll
    for (int i = 0; i < 4; ++i) {
      const int r = (tid >> 4) + 16 * i;   // row 0..63
      const int f = tid & 15;              // float4 column 0..15
      const float4 xv = *(const float4*)(x  + (size_t)(tok0 + r) * MDIM + kc + f * 4);
      *(float4*)(&xs[r][f * 4]) = xv;
      const float4 wv = *(const float4*)(wg + (size_t)r * MDIM + kc + f * 4);
      const int fs = f ^ ((r >> 2) & 7);   // XOR swizzle (bank-conflict-free reads)
      *(float4*)(&wsh[r][fs * 4]) = wv;
    }
    __syncthreads();
#pragma unroll
    for (int k4 = 0; k4 < 16; ++k4) {
      float4 a[4], b[4];
#pragma unroll
      for (int i = 0; i < 4; ++i)
        a[i] = *(const float4*)(&xs[tr * 4 + i][k4 * 4]);
#pragma unroll
      for (int j = 0; j < 4; ++j) {
        const int e  = tc * 4 + j;
        const int fs = k4 ^ ((e >> 2) & 7);
        b[j] = *(const float4*)(&wsh[e][fs * 4]);
      }
#pragma unroll
      for (int i = 0; i < 4; ++i)
#pragma unroll
        for (int j = 0; j < 4; ++j)
          acc[i][j] += a[i].x * b[j].x + a[i].y * b[j].y +
                       a[i].z * b[j].z + a[i].w * b[j].w;
    }
  }

  __syncthreads();
#pragma unroll
  for (int i = 0; i < 4; ++i)
#pragma unroll
    for (int j = 0; j < 4; ++j)
      xs[tr * 4 + i][tc * 4 + j] = acc[i][j];
  __syncthreads();

  if (tid < 64) {
    const int t = tid;
    float mx = -3.0e38f; int am = 0;
    for (int e = 0; e < NEXP; ++e) {
      const float v = xs[t][e];
      if (v > mx) { mx = v; am = e; }   // strict '>' == jnp.argmax first-max
    }
    float sum = 0.f;
    for (int e = 0; e < NEXP; ++e) {
      const float g = expf(xs[t][e] - mx);
      xs[t][e] = g;
      sum += g;
    }
    const float inv = 1.0f / sum;        // gate at argmax == alpha
    for (int e = 0; e < NEXP; ++e) xs[t][e] *= inv;

    const int s = tok0 + t;
    expert_ws[s] = am;
    alpha_ws[s]  = inv;
    out[AL_OFF + s] = inv;
    uval_ws[s] = jax_u01((uint32_t)s * (uint32_t)NEXP + (uint32_t)am);
  }
  __syncthreads();

  if (tid < 64) {
    float s = 0.f;
    for (int t = 0; t < 64; ++t) s += xs[t][tid];
    colsum_ws[(size_t)blockIdx.x * 64 + tid] = s;
  }
}

// ---------------- K2: per-expert capacity selection -> compact slotj table ----------------
// slotj_ws[s] = e*CAP + slot if token kept, else -1. Also exp_counts (pre-capacity).
__global__ __launch_bounds__(256) void k_select(
    const int* __restrict__ expert_ws, const float* __restrict__ uval_ws,
    int* __restrict__ slotj_ws, int* __restrict__ counts_ws,
    float* __restrict__ out)
{
  __shared__ float su[1024];
  __shared__ int   sidx[1024];
  __shared__ int   skept[1024];
  __shared__ int   scnt;

  const int e   = blockIdx.x;
  const int tid = threadIdx.x;
  if (tid == 0) scnt = 0;
  __syncthreads();

  for (int s = tid; s < S_TOK; s += 256) {
    if (expert_ws[s] == e) {
      const int p = atomicAdd(&scnt, 1);
      if (p < 1024) { su[p] = uval_ws[s]; sidx[p] = s; }  // n ~ 256±16; huge headroom
    }
  }
  __syncthreads();
  const int n = min(scnt, 1024);

  if (tid == 0) {
    counts_ws[e] = scnt;
    out[EC_OFF + e] = (float)scnt;   // exp_counts (pre-capacity)
  }

  for (int t = tid; t < n; t += 256) {
    int keep = 1;
    if (n > CAP) {
      const float ut = su[t];
      const int   it = sidx[t];
      int r = 0;
      for (int j = 0; j < n; ++j) {
        const float uj = su[j];
        r += (uj > ut) || (uj == ut && sidx[j] < it);
      }
      keep = (r < CAP);
    }
    skept[t] = keep;
  }
  __syncthreads();

  for (int t = tid; t < n; t += 256) {
    const int it = sidx[t];
    int sj = -1;
    if (skept[t]) {
      int slot = 0;
      for (int j = 0; j < n; ++j) slot += (skept[j] && (sidx[j] < it));
      sj = e * CAP + slot;
    }
    slotj_ws[it] = sj;
  }
}

// ---------------- K3: fused zero-fill + sparse scatter (the 2.15 GB streaming write) ----
// Block bid: region r = bid>>14 (0=combine_weights, 1=dispatch_mask), token s = bid&16383.
// Row = 16384 floats starting at float index 1 + r*SEC + s*16384 (4B-misaligned by 1).
// Head j=0..2 and tail j=16383 scalar; middle 4095 aligned float4 nontemporal stores.
// Block 0 additionally computes l_aux (disjoint data, no ordering hazard).
__global__ __launch_bounds__(256) void k_write(
    const int* __restrict__ slotj_ws, const float* __restrict__ alpha_ws,
    const float* __restrict__ colsum_ws, const int* __restrict__ counts_ws,
    float* __restrict__ out)
{
  const int bid = blockIdx.x;
  const int tid = threadIdx.x;
  const int s   = bid & (S_TOK - 1);
  const int r   = bid >> 14;

  const size_t f0 = CW_OFF + (size_t)r * SEC + (size_t)s * 16384;
  const int    tj = slotj_ws[s];                  // -1 if dropped
  const float  val = r ? 1.0f : alpha_ws[s];

  if (tid < 3)       out[f0 + tid]   = (tj == tid)   ? val : 0.0f;
  else if (tid == 3) out[f0 + 16383] = (tj == 16383) ? val : 0.0f;

  float* const rowp = out + f0 + 3;               // 16B-aligned
#pragma unroll 4
  for (int q = tid; q < 4095; q += 256) {
    const int jbase = 3 + q * 4;
    floatx4 v = (floatx4)(0.f);
    const int d = tj - jbase;
    if ((unsigned)d < 4u) v[d] = val;
    __builtin_nontemporal_store(v, (floatx4*)(rowp + q * 4));
  }

  // l_aux on block 0, wave 0 (reads K1/K2 results; writes out[0] only)
  if (bid == 0 && tid < 64) {
    const int e = tid;
    float cs = 0.f;
    for (int b = 0; b < 256; ++b) cs += colsum_ws[(size_t)b * 64 + e];
    const float me = cs / (float)S_TOK;
    const float ce = (float)counts_ws[e] / (float)S_TOK;
    float v = me * ce;
#pragma unroll
    for (int off = 32; off > 0; off >>= 1) v += __shfl_down(v, off, 64);
    if (e == 0) out[0] = v * (float)NEXP;
  }
}

// ---------------- launch ----------------
extern "C" void kernel_launch(void* const* d_in, const int* in_sizes, int n_in,
                              void* d_out, int out_size, void* d_ws, size_t ws_size,
                              hipStream_t stream)
{
  const float* x  = (const float*)d_in[0];
  const float* wg = (const float*)d_in[1];
  float* out = (float*)d_out;

  // workspace layout
  char* ws = (char*)d_ws;
  int*   expert_ws = (int*)  (ws + 0);        // S ints
  float* uval_ws   = (float*)(ws + 65536);    // S floats
  float* alpha_ws  = (float*)(ws + 131072);   // S floats
  float* colsum_ws = (float*)(ws + 196608);   // 256*64 floats
  int*   counts_ws = (int*)  (ws + 262144);   // 64 ints
  int*   slotj_ws  = (int*)  (ws + 262400);   // S ints

  k_gate  <<<S_TOK / 64, 256, 0, stream>>>(x, wg, out, expert_ws, uval_ws,
                                           alpha_ws, colsum_ws);
  k_select<<<NEXP,       256, 0, stream>>>(expert_ws, uval_ws, slotj_ws,
                                           counts_ws, out);
  k_write <<<2 * S_TOK,  256, 0, stream>>>(slotj_ws, alpha_ws, colsum_ws,
                                           counts_ws, out);
}

// Round 4
// 533.620 us; speedup vs baseline: 1.3887x; 1.3887x over previous
//
#include <hip/hip_runtime.h>
#include <stdint.h>

// Problem constants (match reference)
#define S_TOK 16384
#define MDIM  1024
#define NEXP  64
#define CAP   256   // ceil(S/E * 1.0), >= MIN_CAPACITY

static constexpr size_t SEC    = (size_t)S_TOK * NEXP * CAP;  // 268435456
static constexpr size_t CW_OFF = 1;                            // combine_weights
static constexpr size_t EC_OFF = 1 + 2 * SEC;                  // exp_counts (as float)
static constexpr size_t AL_OFF = EC_OFF + NEXP;                // alpha

// Fill geometry: zero region = floats [1, 1 + 2*SEC) = 536,870,912 floats.
// Scalars at idx 1,2,3 and idx 536870912; aligned float4 span [4, 536870912)
// = 134,217,727 float4 quads. 32768 fill blocks x 4096 quads (last short by 1).
static constexpr int    NFILLB = 32768;
static constexpr size_t NQ4    = 134217727;

// ---------------- Threefry-2x32-20 == jax.random.uniform(key(42), (S,E)) ----------------
__device__ __forceinline__ uint32_t rotl32(uint32_t x, int n) {
  return (x << n) | (x >> (32 - n));
}

__device__ float jax_u01(uint32_t i) {
  const uint32_t half = (uint32_t)(S_TOK * NEXP / 2);  // 524288
  uint32_t x0, x1;
  const bool hi = (i >= half);
  if (hi) { x0 = i - half; x1 = i; } else { x0 = i; x1 = i + half; }
  const uint32_t ks0 = 0u;
  const uint32_t ks1 = 42u;
  const uint32_t ks2 = 0x1BD11BDAu ^ ks0 ^ ks1;
  x0 += ks0; x1 += ks1;
#define TF_R(r) { x0 += x1; x1 = rotl32(x1, (r)); x1 ^= x0; }
  TF_R(13) TF_R(15) TF_R(26) TF_R(6)
  x0 += ks1; x1 += ks2 + 1u;
  TF_R(17) TF_R(29) TF_R(16) TF_R(24)
  x0 += ks2; x1 += ks0 + 2u;
  TF_R(13) TF_R(15) TF_R(26) TF_R(6)
  x0 += ks0; x1 += ks1 + 3u;
  TF_R(17) TF_R(29) TF_R(16) TF_R(24)
  x0 += ks1; x1 += ks2 + 4u;
  TF_R(13) TF_R(15) TF_R(26) TF_R(6)
  x0 += ks2; x1 += ks0 + 5u;
#undef TF_R
  const uint32_t bits = hi ? x1 : x0;
  return __uint_as_float((bits >> 9) | 0x3F800000u) - 1.0f;  // [0,1)
}

// ---------------- K1: fused {zero-fill 2.15 GB} + {gate GEMM/softmax} ----------------
// Blocks 0..255: gate (64 tokens each). Blocks 256..256+NFILLB-1: streaming zero-fill.
// Gate compute (~45us) hides under the fill (~340us); fill blocks are pure aligned
// float4 zero stores (fillBuffer pattern — no compares, no NT, no dynamic indexing).
__global__ __launch_bounds__(256) void k_gate_fill(
    const float* __restrict__ x, const float* __restrict__ wg,
    float* __restrict__ out,
    int* __restrict__ expert_ws, float* __restrict__ uval_ws,
    float* __restrict__ alpha_ws, float* __restrict__ colsum_ws)
{
  __shared__ float xs[64][68];   // 68-float rows keep float4 slots 16B-aligned
  __shared__ float wsh[64][68];

  const int tid = threadIdx.x;

  if (blockIdx.x >= 256) {
    // ---------------- fill path ----------------
    const int fb = blockIdx.x - 256;
    const size_t qbase = (size_t)fb * 4096;
    const float4 z = make_float4(0.f, 0.f, 0.f, 0.f);
    float* const p4 = out + 4;   // 16B-aligned base of quad span
#pragma unroll 4
    for (int i = 0; i < 16; ++i) {
      const size_t q = qbase + (size_t)(i * 256 + tid);
      if (q < NQ4) *(float4*)(p4 + q * 4) = z;
    }
    if (fb == 0) {
      if (tid < 3)       out[1 + tid]          = 0.f;
      else if (tid == 3) out[1 + 2 * SEC - 1]  = 0.f;
    }
    return;
  }

  // ---------------- gate path (blocks 0..255) ----------------
  const int tok0 = blockIdx.x * 64;
  const int tr   = tid >> 4;   // token group 0..15 (4 tokens each)
  const int tc   = tid & 15;   // expert group 0..15 (4 experts each)

  float acc[4][4] = {};

  for (int kc = 0; kc < MDIM; kc += 64) {
    __syncthreads();
#pragma unroll
    for (int i = 0; i < 4; ++i) {
      const int r = (tid >> 4) + 16 * i;   // row 0..63
      const int f = tid & 15;              // float4 column 0..15
      const float4 xv = *(const float4*)(x  + (size_t)(tok0 + r) * MDIM + kc + f * 4);
      *(float4*)(&xs[r][f * 4]) = xv;
      const float4 wv = *(const float4*)(wg + (size_t)r * MDIM + kc + f * 4);
      const int fs = f ^ ((r >> 2) & 7);   // XOR swizzle (bank-conflict-free reads)
      *(float4*)(&wsh[r][fs * 4]) = wv;
    }
    __syncthreads();
#pragma unroll
    for (int k4 = 0; k4 < 16; ++k4) {
      float4 a[4], b[4];
#pragma unroll
      for (int i = 0; i < 4; ++i)
        a[i] = *(const float4*)(&xs[tr * 4 + i][k4 * 4]);
#pragma unroll
      for (int j = 0; j < 4; ++j) {
        const int e  = tc * 4 + j;
        const int fs = k4 ^ ((e >> 2) & 7);
        b[j] = *(const float4*)(&wsh[e][fs * 4]);
      }
#pragma unroll
      for (int i = 0; i < 4; ++i)
#pragma unroll
        for (int j = 0; j < 4; ++j)
          acc[i][j] += a[i].x * b[j].x + a[i].y * b[j].y +
                       a[i].z * b[j].z + a[i].w * b[j].w;
    }
  }

  __syncthreads();
#pragma unroll
  for (int i = 0; i < 4; ++i)
#pragma unroll
    for (int j = 0; j < 4; ++j)
      xs[tr * 4 + i][tc * 4 + j] = acc[i][j];
  __syncthreads();

  if (tid < 64) {
    const int t = tid;
    float mx = -3.0e38f; int am = 0;
    for (int e = 0; e < NEXP; ++e) {
      const float v = xs[t][e];
      if (v > mx) { mx = v; am = e; }   // strict '>' == jnp.argmax first-max
    }
    float sum = 0.f;
    for (int e = 0; e < NEXP; ++e) {
      const float g = expf(xs[t][e] - mx);
      xs[t][e] = g;
      sum += g;
    }
    const float inv = 1.0f / sum;        // gate at argmax == alpha
    for (int e = 0; e < NEXP; ++e) xs[t][e] *= inv;

    const int s = tok0 + t;
    expert_ws[s] = am;
    alpha_ws[s]  = inv;
    out[AL_OFF + s] = inv;
    uval_ws[s] = jax_u01((uint32_t)s * (uint32_t)NEXP + (uint32_t)am);
  }
  __syncthreads();

  if (tid < 64) {
    float s = 0.f;
    for (int t = 0; t < 64; ++t) s += xs[t][tid];
    colsum_ws[(size_t)blockIdx.x * 64 + tid] = s;
  }
}

// ---------------- K2: per-expert capacity selection + sparse scatter ----------------
// Runs after K1 (stream order): scatters ~16K nonzeros into the zeroed buffer.
__global__ __launch_bounds__(256) void k_select(
    const int* __restrict__ expert_ws, const float* __restrict__ uval_ws,
    const float* __restrict__ alpha_ws, int* __restrict__ counts_ws,
    float* __restrict__ out)
{
  __shared__ float su[1024];
  __shared__ int   sidx[1024];
  __shared__ int   skept[1024];
  __shared__ int   scnt;

  const int e   = blockIdx.x;
  const int tid = threadIdx.x;
  if (tid == 0) scnt = 0;
  __syncthreads();

  for (int s = tid; s < S_TOK; s += 256) {
    if (expert_ws[s] == e) {
      const int p = atomicAdd(&scnt, 1);
      if (p < 1024) { su[p] = uval_ws[s]; sidx[p] = s; }  // n ~ 256±16; huge headroom
    }
  }
  __syncthreads();
  const int n = min(scnt, 1024);

  if (tid == 0) {
    counts_ws[e] = scnt;
    out[EC_OFF + e] = (float)scnt;   // exp_counts (pre-capacity)
  }

  for (int t = tid; t < n; t += 256) {
    int keep = 1;
    if (n > CAP) {
      const float ut = su[t];
      const int   it = sidx[t];
      int r = 0;
      for (int j = 0; j < n; ++j) {
        const float uj = su[j];
        r += (uj > ut) || (uj == ut && sidx[j] < it);
      }
      keep = (r < CAP);
    }
    skept[t] = keep;
  }
  __syncthreads();

  for (int t = tid; t < n; t += 256) {
    if (!skept[t]) continue;
    const int it = sidx[t];
    int slot = 0;
    for (int j = 0; j < n; ++j) slot += (skept[j] && (sidx[j] < it));
    const size_t base = CW_OFF + ((size_t)it * NEXP + e) * CAP + (size_t)slot;
    out[base]       = alpha_ws[it];  // combine_weights
    out[base + SEC] = 1.0f;          // dispatch_mask (bool as 1.0f)
  }
}

// ---------------- K3: l_aux ----------------
__global__ __launch_bounds__(64) void k_final(
    const float* __restrict__ colsum_ws, const int* __restrict__ counts_ws,
    float* __restrict__ out)
{
  const int e = threadIdx.x;  // 0..63
  float s = 0.f;
  for (int b = 0; b < 256; ++b) s += colsum_ws[(size_t)b * 64 + e];  // fixed order
  const float me = s / (float)S_TOK;
  const float ce = (float)counts_ws[e] / (float)S_TOK;
  float v = me * ce;
#pragma unroll
  for (int off = 32; off > 0; off >>= 1) v += __shfl_down(v, off, 64);
  if (e == 0) out[0] = v * (float)NEXP;
}

// ---------------- launch ----------------
extern "C" void kernel_launch(void* const* d_in, const int* in_sizes, int n_in,
                              void* d_out, int out_size, void* d_ws, size_t ws_size,
                              hipStream_t stream)
{
  const float* x  = (const float*)d_in[0];
  const float* wg = (const float*)d_in[1];
  float* out = (float*)d_out;

  // workspace layout
  char* ws = (char*)d_ws;
  int*   expert_ws = (int*)  (ws + 0);        // S ints
  float* uval_ws   = (float*)(ws + 65536);    // S floats
  float* alpha_ws  = (float*)(ws + 131072);   // S floats
  float* colsum_ws = (float*)(ws + 196608);   // 256*64 floats
  int*   counts_ws = (int*)  (ws + 262144);   // 64 ints

  k_gate_fill<<<256 + NFILLB, 256, 0, stream>>>(x, wg, out, expert_ws, uval_ws,
                                                alpha_ws, colsum_ws);
  k_select   <<<NEXP,         256, 0, stream>>>(expert_ws, uval_ws, alpha_ws,
                                                counts_ws, out);
  k_final    <<<1,             64, 0, stream>>>(colsum_ws, counts_ws, out);
}